// Round 3
// baseline (609.789 us; speedup 1.0000x reference)
//
#include <hip/hip_runtime.h>
#include <hip/hip_cooperative_groups.h>

namespace cg = cooperative_groups;

#define GRID   256           // cooperative grid: 1 block/CU, all co-resident
#define TPB    512           // 8 waves
#define DCHUNK 16384         // edges per deg-count block -> nscat = 98

// Phases (grid.sync between):
// P0: blocks[0,nscat): deg[dst]++ (rank=old) | blocks[nscat,GRID): fold + dots (ga,gbc,c01)
// P1: per-block exclusive scan of deg (512 nodes/block) -> off_p + part
// P2: block 0 scans part[] -> part2[]   (true offset = off_p[n] + part2[n>>9])
// P4: placement: sorted[off(dst)+rank[e]] = src[e]    (no atomics)
// P5: per-node gather-sum of gbc over sorted in-edges -> q, t1   (no atomics)
// P6: per-node gather-sum of q -> out                            (no atomics)
__global__ __launch_bounds__(TPB) void mega_kernel(
    const float* __restrict__ x,
    const int* __restrict__ src, const int* __restrict__ dst,
    int E, int N, int nscat, int nscan,
    int* __restrict__ deg, unsigned char* rank,
    int* __restrict__ off_p, int* __restrict__ part, int* __restrict__ part2,
    int* __restrict__ sorted,
    const float* __restrict__ Wl1, const float* __restrict__ Wr1, const float* __restrict__ b1,
    const float* __restrict__ Wl2, const float* __restrict__ Wr2, const float* __restrict__ b2,
    const float* __restrict__ Wfc1, const float* __restrict__ bfc1,
    const float* __restrict__ Wfc2, const float* __restrict__ bfc2,
    float* __restrict__ ga, float2* __restrict__ gbc, float* __restrict__ c01,
    float* q, float* t1, float* __restrict__ outp)
{
    __shared__ __align__(16) float wv[192];
    __shared__ float uu[128], vl2[128], vr2[128], w2[32];
    __shared__ int scanbuf[TPB];
    __shared__ int pbuf[256];
    cg::grid_group grid = cg::this_grid();
    int t = threadIdx.x;
    int l = t & 63;          // lane
    int w = t >> 6;          // wave (0..7)
    int bid = blockIdx.x;

    // ================= P0 =================
    if (bid < nscat) {
        // ---- deg count + per-edge rank (global L2-side atomics, coalesced reads/writes) ----
        int e0 = bid * DCHUNK;
        int cnt = E - e0; if (cnt > DCHUNK) cnt = DCHUNK;
        int i = t;
        for (; i + 3 * TPB < cnt; i += 4 * TPB) {
            int d0 = dst[e0 + i], d1 = dst[e0 + i + TPB];
            int d2 = dst[e0 + i + 2 * TPB], d3 = dst[e0 + i + 3 * TPB];
            int r0 = atomicAdd(&deg[d0], 1);
            int r1 = atomicAdd(&deg[d1], 1);
            int r2 = atomicAdd(&deg[d2], 1);
            int r3 = atomicAdd(&deg[d3], 1);
            rank[e0 + i]           = (unsigned char)r0;
            rank[e0 + i + TPB]     = (unsigned char)r1;
            rank[e0 + i + 2 * TPB] = (unsigned char)r2;
            rank[e0 + i + 3 * TPB] = (unsigned char)r3;
        }
        for (; i < cnt; i += TPB)
            rank[e0 + i] = (unsigned char)atomicAdd(&deg[dst[e0 + i]], 1);
    } else {
        // ---- fold role (8-wave version, redundant per dots block) ----
        if (t < 32) w2[t] = Wfc2[t];
        __syncthreads();
        for (int j = 0; j < 16; ++j) {   // uu = Wfc1 @ Wfc2  (Wfc1 [128,32] row-major)
            int ii = w + 8 * j;
            float p = (l < 32) ? Wfc1[ii * 32 + l] * w2[l] : 0.f;
            for (int m = 16; m; m >>= 1) p += __shfl_xor(p, m);
            if (l == 0) uu[ii] = p;
        }
        __syncthreads();
        for (int j = 0; j < 16; ++j) {   // vl2 = Wl2 @ uu, vr2 = Wr2 @ uu ([128,128] row-major)
            int ii = w + 8 * j;
            float ua = uu[l], ub = uu[64 + l];
            float pa = Wl2[ii * 128 + l] * ua + Wl2[ii * 128 + 64 + l] * ub;
            float pb = Wr2[ii * 128 + l] * ua + Wr2[ii * 128 + 64 + l] * ub;
            for (int m = 32; m; m >>= 1) { pa += __shfl_xor(pa, m); pb += __shfl_xor(pb, m); }
            if (l == 0) { vl2[ii] = pa; vr2[ii] = pb; }
        }
        __syncthreads();
        for (int j = 0; j < 8; ++j) {    // wv = {w_a,w_b,w_c}  (Wl1/Wr1 [64,128] row-major)
            int ii = w + 8 * j;
            float l1a = Wl1[ii * 128 + l], l1b = Wl1[ii * 128 + 64 + l];
            float r1a = Wr1[ii * 128 + l], r1b = Wr1[ii * 128 + 64 + l];
            float La = vl2[l], Lb = vl2[64 + l], Ra = vr2[l], Rb = vr2[64 + l];
            float pc = l1a * La + l1b * Lb;
            float pb = l1a * Ra + l1b * Rb + r1a * La + r1b * Lb;
            float pa = r1a * Ra + r1b * Rb;
            for (int m = 32; m; m >>= 1) {
                pa += __shfl_xor(pa, m); pb += __shfl_xor(pb, m); pc += __shfl_xor(pc, m);
            }
            if (l == 0) { wv[ii] = pa; wv[64 + ii] = pb; wv[128 + ii] = pc; }
        }
        if (bid == nscat && w == 7) {    // c0, c1 (one block publishes)
            float p0 = b1[l] * vr2[l] + b1[64 + l] * vr2[64 + l]
                     + b2[l] * uu[l] + b2[64 + l] * uu[64 + l];
            if (l < 32) p0 += bfc1[l] * w2[l];
            float p1 = b1[l] * vl2[l] + b1[64 + l] * vl2[64 + l];
            for (int m = 32; m; m >>= 1) { p0 += __shfl_xor(p0, m); p1 += __shfl_xor(p1, m); }
            if (l == 0) { c01[0] = p0 + bfc2[0]; c01[1] = p1; }
        }
        __syncthreads();

        // ---- dots: 4 nodes/wave, float4, 16 lanes per node ----
        int fp = l & 15, sub = l >> 4;
        float4 wa4 = ((const float4*)wv)[fp];
        float4 wb4 = ((const float4*)wv)[16 + fp];
        float4 wc4 = ((const float4*)wv)[32 + fp];
        const float4* x4 = (const float4*)x;
        int Q = (N + 3) >> 2;
        int ndot = GRID - nscat;
        int wid = (bid - nscat) * 8 + w;
        int stride = ndot * 8;
        for (int qd = wid; qd < Q; qd += stride) {
            int node = qd * 4 + sub;
            float a = 0.f, b = 0.f, c = 0.f;
            if (node < N) {
                float4 v = x4[(size_t)node * 16 + fp];
                a = v.x * wa4.x + v.y * wa4.y + v.z * wa4.z + v.w * wa4.w;
                b = v.x * wb4.x + v.y * wb4.y + v.z * wb4.z + v.w * wb4.w;
                c = v.x * wc4.x + v.y * wc4.y + v.z * wc4.z + v.w * wc4.w;
            }
            for (int m = 8; m; m >>= 1) {
                a += __shfl_xor(a, m); b += __shfl_xor(b, m); c += __shfl_xor(c, m);
            }
            if (fp == 0 && node < N) { ga[node] = a; gbc[node] = make_float2(b, c); }
        }
    }
    __threadfence();
    grid.sync();

    // ================= P1: block-local exclusive scan of deg =================
    if (bid < nscan) {
        int node = bid * TPB + t;
        int val = (node < N) ? deg[node] : 0;
        scanbuf[t] = val;
        __syncthreads();
        for (int d2 = 1; d2 < TPB; d2 <<= 1) {
            int xx = (t >= d2) ? scanbuf[t - d2] : 0;
            __syncthreads();
            scanbuf[t] += xx;
            __syncthreads();
        }
        int incl = scanbuf[t];
        if (node < N) off_p[node] = incl - val;
        if (t == TPB - 1) part[bid] = incl;
    }
    __threadfence();
    grid.sync();

    // ================= P2: block 0 scans the 196 partials =================
    if (bid == 0) {
        int val = (t < nscan) ? part[t] : 0;
        if (t < 256) pbuf[t] = val;
        __syncthreads();
        for (int d2 = 1; d2 < 256; d2 <<= 1) {
            int xx = (t >= d2 && t < 256) ? pbuf[t - d2] : 0;
            __syncthreads();
            if (t < 256) pbuf[t] += xx;
            __syncthreads();
        }
        if (t < nscan) part2[t] = pbuf[t] - val;
    }
    __threadfence();
    grid.sync();

    // ================= P4: placement (no atomics) =================
    {
        int stride = GRID * TPB;
        for (int e = bid * TPB + t; e < E; e += stride) {
            int d = dst[e];
            int pos = off_p[d] + part2[d >> 9] + (int)rank[e];
            sorted[pos] = src[e];
        }
    }
    __threadfence();
    grid.sync();

    // ================= P5: agg1 — per-node gather-sum (no atomics) =================
    {
        int node = bid * TPB + t;
        if (node < N) {
            int dg = deg[node];
            int base = off_p[node] + part2[node >> 9];
            float sb = 0.f, sc = 0.f;
            int k = 0;
            for (; k + 4 <= dg; k += 4) {
                int s0 = sorted[base + k],     s1 = sorted[base + k + 1];
                int s2 = sorted[base + k + 2], s3 = sorted[base + k + 3];
                float2 g0 = gbc[s0], g1 = gbc[s1], g2 = gbc[s2], g3 = gbc[s3];
                sb += (g0.x + g1.x) + (g2.x + g3.x);
                sc += (g0.y + g1.y) + (g2.y + g3.y);
            }
            for (; k < dg; ++k) { float2 g = gbc[sorted[base + k]]; sb += g.x; sc += g.y; }
            float iv = 1.0f / ((dg > 0) ? (float)dg : 1.0f);
            q[node]  = iv * sc;
            t1[node] = ga[node] + iv * sb + c01[0] + (dg > 0 ? c01[1] : 0.f);
        }
    }
    __threadfence();
    grid.sync();

    // ================= P6: agg2 — per-node gather-sum of q (no atomics) =================
    {
        int node = bid * TPB + t;
        if (node < N) {
            int dg = deg[node];
            int base = off_p[node] + part2[node >> 9];
            float s2 = 0.f;
            int k = 0;
            for (; k + 4 <= dg; k += 4) {
                float q0 = q[sorted[base + k]],     q1 = q[sorted[base + k + 1]];
                float q2 = q[sorted[base + k + 2]], q3 = q[sorted[base + k + 3]];
                s2 += (q0 + q1) + (q2 + q3);
            }
            for (; k < dg; ++k) s2 += q[sorted[base + k]];
            float iv = 1.0f / ((dg > 0) ? (float)dg : 1.0f);
            outp[node] = t1[node] + iv * s2;
        }
    }
}

extern "C" void kernel_launch(void* const* d_in, const int* in_sizes, int n_in,
                              void* d_out, int out_size, void* d_ws, size_t ws_size,
                              hipStream_t stream) {
    const float* x    = (const float*)d_in[0];
    const int*   eidx = (const int*)d_in[1];   // [2, E]
    // d_in[2] = edge_weight: unused by the reference
    const float* Wl1  = (const float*)d_in[3];
    const float* Wr1  = (const float*)d_in[4];
    const float* b1   = (const float*)d_in[5];
    const float* Wl2  = (const float*)d_in[6];
    const float* Wr2  = (const float*)d_in[7];
    const float* b2   = (const float*)d_in[8];
    const float* Wfc1 = (const float*)d_in[9];
    const float* bfc1 = (const float*)d_in[10];
    const float* Wfc2 = (const float*)d_in[11];
    const float* bfc2 = (const float*)d_in[12];

    const int N = in_sizes[0] / 64;
    const int E = in_sizes[2];
    const int* src = eidx;
    const int* dst = eidx + E;
    const int nscat = (E + DCHUNK - 1) / DCHUNK;   // 98 deg-count blocks
    const int nscan = (N + TPB - 1) / TPB;         // 196 scan blocks

    // workspace layout (all 128B-aligned):
    // [deg N*4][rank E*1 (q,t1 overlay after P4)][off_p N*4][part 1K][part2 1K][c01 64B]
    // [ga N*4][gbc N*8][sorted E*4]   total ~= 9.6 MB
    char* ws = (char*)d_ws;
    size_t o = 0;
    auto take = [&](size_t bytes) { char* p = ws + o; o += (bytes + 127) & ~(size_t)127; return p; };
    int*           deg    = (int*)take((size_t)N * 4);
    unsigned char* rank   = (unsigned char*)take((size_t)E);
    int*           off_p  = (int*)take((size_t)N * 4);
    int*           part   = (int*)take(1024);
    int*           part2  = (int*)take(1024);
    float*         c01    = (float*)take(64);
    float*         ga     = (float*)take((size_t)N * 4);
    float2*        gbc    = (float2*)take((size_t)N * 8);
    int*           sorted = (int*)take((size_t)E * 4);
    // q/t1 overlay rank's region (rank is dead after P4; phases separated by grid.sync)
    float* q  = (float*)rank;
    float* t1 = ((float*)rank) + N;
    float* outp = (float*)d_out;

    hipMemsetAsync(deg, 0, (size_t)N * 4, stream);

    int E_ = E, N_ = N, nscat_ = nscat, nscan_ = nscan;
    void* args[] = {
        (void*)&x, (void*)&src, (void*)&dst, (void*)&E_, (void*)&N_, (void*)&nscat_, (void*)&nscan_,
        (void*)&deg, (void*)&rank, (void*)&off_p, (void*)&part, (void*)&part2, (void*)&sorted,
        (void*)&Wl1, (void*)&Wr1, (void*)&b1, (void*)&Wl2, (void*)&Wr2, (void*)&b2,
        (void*)&Wfc1, (void*)&bfc1, (void*)&Wfc2, (void*)&bfc2,
        (void*)&ga, (void*)&gbc, (void*)&c01, (void*)&q, (void*)&t1, (void*)&outp
    };
    hipLaunchCooperativeKernel(reinterpret_cast<void*>(mega_kernel),
                               dim3(GRID), dim3(TPB), args, 0, stream);
}

// Round 4
// 227.330 us; speedup vs baseline: 2.6824x; 2.6824x over previous
//
#include <hip/hip_runtime.h>

#define S_SHIFT 7
#define S_NODES 128          // nodes per bucket (dst_local = dst & 127)
#define NBKT    784          // LDS/array size (>= B = 782)
#define CAP     2560         // bucket capacity (mean ~2046, +25% slack)
#define CHUNK   8192         // edges per scatter block
#define NREP    4            // LDS accumulator replicas in agg kernels (256 thr)
#define FTH     512          // fused kernel block size (8 waves)
#define ATH     256          // agg kernel block size (4 waves)
#define NDOTS   160          // dots-role blocks

// ---------------- fused: scatter role [0,nscat) + fold/dots role [nscat,nscat+NDOTS) ----------------
// Packed edge: (src << 7) | (dst & 127)   (src < 2^17 -> 24 bits)
__global__ __launch_bounds__(FTH) void fused_kernel(
    const float* __restrict__ x,
    const int* __restrict__ src, const int* __restrict__ dst,
    int E, int N, int B, int nscat,
    int* __restrict__ cursor, int* __restrict__ deg, unsigned* __restrict__ bucket,
    const float* __restrict__ Wl1, const float* __restrict__ Wr1, const float* __restrict__ b1,
    const float* __restrict__ Wl2, const float* __restrict__ Wr2, const float* __restrict__ b2,
    const float* __restrict__ Wfc1, const float* __restrict__ bfc1,
    const float* __restrict__ Wfc2, const float* __restrict__ bfc2,
    float* __restrict__ ga, float2* __restrict__ gbc, float* __restrict__ c01)
{
    __shared__ int hist[NBKT], lbase[NBKT], lcur[NBKT];          // scatter role
    __shared__ __align__(16) float wv[192];                      // dots role
    __shared__ float uu[128], vl2[128], vr2[128], w2[32];
    int t = threadIdx.x;
    int l = t & 63;          // lane
    int w = t >> 6;          // wave (0..7)
    int bid = blockIdx.x;

    if (bid < nscat) {
        // ---------------- scatter role ----------------
        int e0 = bid * CHUNK;
        int cnt = E - e0; if (cnt > CHUNK) cnt = CHUNK;
        for (int i = t; i < B; i += FTH) hist[i] = 0;
        __syncthreads();
        for (int i = t; i < cnt; i += FTH) {
            int d = dst[e0 + i];
            atomicAdd(&hist[d >> S_SHIFT], 1);
            atomicAdd(&deg[d], 1);            // fire-and-forget (L2-side, result unused)
        }
        __syncthreads();
        for (int i = t; i < B; i += FTH) {
            lcur[i] = 0;
            if (hist[i] > 0) lbase[i] = atomicAdd(&cursor[i], hist[i]);
        }
        __syncthreads();
        for (int i = t; i < cnt; i += FTH) {
            int d = dst[e0 + i], s = src[e0 + i];   // L2-hot re-read
            int bb = d >> S_SHIFT;
            int off = atomicAdd(&lcur[bb], 1);
            bucket[(size_t)bb * CAP + (unsigned)(lbase[bb] + off)] =
                ((unsigned)s << S_SHIFT) | (unsigned)(d & (S_NODES - 1));
        }
    } else {
        // ---------------- fold role (8-wave, redundant per block, hidden under scatter) ----------------
        if (t < 32) w2[t] = Wfc2[t];
        __syncthreads();
        for (int j = 0; j < 16; ++j) {   // uu = Wfc1 @ Wfc2  (Wfc1 [128,32] row-major)
            int i = w + 8 * j;
            float p = (l < 32) ? Wfc1[i * 32 + l] * w2[l] : 0.f;
            for (int m = 16; m; m >>= 1) p += __shfl_xor(p, m);
            if (l == 0) uu[i] = p;
        }
        __syncthreads();
        for (int j = 0; j < 16; ++j) {   // vl2 = Wl2 @ uu, vr2 = Wr2 @ uu ([128,128] row-major)
            int i = w + 8 * j;
            float ua = uu[l], ub = uu[64 + l];
            float pa = Wl2[i * 128 + l] * ua + Wl2[i * 128 + 64 + l] * ub;
            float pb = Wr2[i * 128 + l] * ua + Wr2[i * 128 + 64 + l] * ub;
            for (int m = 32; m; m >>= 1) { pa += __shfl_xor(pa, m); pb += __shfl_xor(pb, m); }
            if (l == 0) { vl2[i] = pa; vr2[i] = pb; }
        }
        __syncthreads();
        for (int j = 0; j < 8; ++j) {    // wv = {w_a,w_b,w_c}  (Wl1/Wr1 [64,128] row-major)
            int i = w + 8 * j;
            float l1a = Wl1[i * 128 + l], l1b = Wl1[i * 128 + 64 + l];
            float r1a = Wr1[i * 128 + l], r1b = Wr1[i * 128 + 64 + l];
            float La = vl2[l], Lb = vl2[64 + l], Ra = vr2[l], Rb = vr2[64 + l];
            float pc = l1a * La + l1b * Lb;
            float pb = l1a * Ra + l1b * Rb + r1a * La + r1b * Lb;
            float pa = r1a * Ra + r1b * Rb;
            for (int m = 32; m; m >>= 1) {
                pa += __shfl_xor(pa, m); pb += __shfl_xor(pb, m); pc += __shfl_xor(pc, m);
            }
            if (l == 0) { wv[i] = pa; wv[64 + i] = pb; wv[128 + i] = pc; }
        }
        if (bid == nscat && w == 7) {    // c0, c1 (one block publishes)
            float p0 = b1[l] * vr2[l] + b1[64 + l] * vr2[64 + l]
                     + b2[l] * uu[l] + b2[64 + l] * uu[64 + l];
            if (l < 32) p0 += bfc1[l] * w2[l];
            float p1 = b1[l] * vl2[l] + b1[64 + l] * vl2[64 + l];
            for (int m = 32; m; m >>= 1) { p0 += __shfl_xor(p0, m); p1 += __shfl_xor(p1, m); }
            if (l == 0) { c01[0] = p0 + bfc2[0]; c01[1] = p1; }
        }
        __syncthreads();

        // ---------------- dots: 4 nodes/wave, float4, 16 lanes per node ----------------
        int fp = l & 15, sub = l >> 4;
        float4 wa4 = ((const float4*)wv)[fp];
        float4 wb4 = ((const float4*)wv)[16 + fp];
        float4 wc4 = ((const float4*)wv)[32 + fp];
        const float4* x4 = (const float4*)x;
        int Q = (N + 3) >> 2;
        for (int qd = (bid - nscat) * 8 + w; qd < Q; qd += NDOTS * 8) {
            int node = qd * 4 + sub;
            float a = 0.f, b = 0.f, c = 0.f;
            if (node < N) {
                float4 v = x4[(size_t)node * 16 + fp];
                a = v.x * wa4.x + v.y * wa4.y + v.z * wa4.z + v.w * wa4.w;
                b = v.x * wb4.x + v.y * wb4.y + v.z * wb4.z + v.w * wb4.w;
                c = v.x * wc4.x + v.y * wc4.y + v.z * wc4.z + v.w * wc4.w;
            }
            for (int m = 8; m; m >>= 1) {
                a += __shfl_xor(a, m); b += __shfl_xor(b, m); c += __shfl_xor(c, m);
            }
            if (fp == 0 && node < N) { ga[node] = a; gbc[node] = make_float2(b, c); }
        }
    }
}

// One block per bucket, 256 threads, per-wave (4x) replicated LDS accumulators.
// Pipelined uint4 reads; degree comes from global deg[] (counted in scatter) -> no cnt atomics.
__global__ __launch_bounds__(ATH) void aggA_kernel(
    const unsigned* __restrict__ bucket, const int* __restrict__ cursor,
    const int* __restrict__ deg,
    const float2* __restrict__ gbc, const float* __restrict__ ga,
    const float* __restrict__ c01,
    float* __restrict__ q, float* __restrict__ t1, float* __restrict__ inv, int N)
{
    __shared__ float aB[NREP][S_NODES], aC[NREP][S_NODES];
    int t = threadIdx.x, b = blockIdx.x;
    int r = t >> 6;                       // private replica per wave
    float* aBf = (float*)aB; float* aCf = (float*)aC;
    for (int i = t; i < NREP * S_NODES; i += ATH) { aBf[i] = 0.f; aCf[i] = 0.f; }
    __syncthreads();
    int n = cursor[b];
    const unsigned* bp = bucket + (size_t)b * CAP;
    int n4 = n & ~3;
    int i = 4 * t;
    bool have = i < n4;
    uint4 cur = make_uint4(0, 0, 0, 0);
    if (have) cur = *(const uint4*)(bp + i);
    while (have) {
        int in2 = i + 4 * ATH;
        bool hn = in2 < n4;
        uint4 nxt = cur;
        if (hn) nxt = *(const uint4*)(bp + in2);
        float2 g0 = gbc[cur.x >> S_SHIFT];
        float2 g1 = gbc[cur.y >> S_SHIFT];
        float2 g2 = gbc[cur.z >> S_SHIFT];
        float2 g3 = gbc[cur.w >> S_SHIFT];
        int d0 = cur.x & (S_NODES - 1), d1 = cur.y & (S_NODES - 1);
        int d2 = cur.z & (S_NODES - 1), d3 = cur.w & (S_NODES - 1);
        atomicAdd(&aB[r][d0], g0.x); atomicAdd(&aC[r][d0], g0.y);
        atomicAdd(&aB[r][d1], g1.x); atomicAdd(&aC[r][d1], g1.y);
        atomicAdd(&aB[r][d2], g2.x); atomicAdd(&aC[r][d2], g2.y);
        atomicAdd(&aB[r][d3], g3.x); atomicAdd(&aC[r][d3], g3.y);
        cur = nxt; i = in2; have = hn;
    }
    if (n4 + t < n) {
        unsigned uu = bp[n4 + t];
        float2 g = gbc[uu >> S_SHIFT];
        int dl = uu & (S_NODES - 1);
        atomicAdd(&aB[r][dl], g.x); atomicAdd(&aC[r][dl], g.y);
    }
    __syncthreads();
    if (t < S_NODES) {
        int node = (b << S_SHIFT) + t;
        if (node < N) {
            float sb = 0.f, sc = 0.f;
            #pragma unroll
            for (int k = 0; k < NREP; ++k) { sb += aB[k][t]; sc += aC[k][t]; }
            int d = deg[node];
            float iv = 1.0f / ((d > 0) ? (float)d : 1.0f);
            inv[node] = iv;
            q[node]   = iv * sc;
            t1[node]  = ga[node] + iv * sb + c01[0] + (d > 0 ? c01[1] : 0.f);
        }
    }
}

__global__ __launch_bounds__(ATH) void aggB_kernel(
    const unsigned* __restrict__ bucket, const int* __restrict__ cursor,
    const float* __restrict__ q, const float* __restrict__ t1,
    const float* __restrict__ inv, float* __restrict__ out, int N)
{
    __shared__ float a2[NREP][S_NODES];
    int t = threadIdx.x, b = blockIdx.x;
    int r = t >> 6;
    float* a2f = (float*)a2;
    for (int i = t; i < NREP * S_NODES; i += ATH) a2f[i] = 0.f;
    __syncthreads();
    int n = cursor[b];
    const unsigned* bp = bucket + (size_t)b * CAP;
    int n4 = n & ~3;
    int i = 4 * t;
    bool have = i < n4;
    uint4 cur = make_uint4(0, 0, 0, 0);
    if (have) cur = *(const uint4*)(bp + i);
    while (have) {
        int in2 = i + 4 * ATH;
        bool hn = in2 < n4;
        uint4 nxt = cur;
        if (hn) nxt = *(const uint4*)(bp + in2);
        float q0 = q[cur.x >> S_SHIFT], q1 = q[cur.y >> S_SHIFT];
        float q2 = q[cur.z >> S_SHIFT], q3 = q[cur.w >> S_SHIFT];
        atomicAdd(&a2[r][cur.x & (S_NODES - 1)], q0);
        atomicAdd(&a2[r][cur.y & (S_NODES - 1)], q1);
        atomicAdd(&a2[r][cur.z & (S_NODES - 1)], q2);
        atomicAdd(&a2[r][cur.w & (S_NODES - 1)], q3);
        cur = nxt; i = in2; have = hn;
    }
    if (n4 + t < n) {
        unsigned uu = bp[n4 + t];
        atomicAdd(&a2[r][uu & (S_NODES - 1)], q[uu >> S_SHIFT]);
    }
    __syncthreads();
    if (t < S_NODES) {
        int node = (b << S_SHIFT) + t;
        if (node < N) {
            float s2 = 0.f;
            #pragma unroll
            for (int k = 0; k < NREP; ++k) s2 += a2[k][t];
            out[node] = t1[node] + inv[node] * s2;
        }
    }
}

extern "C" void kernel_launch(void* const* d_in, const int* in_sizes, int n_in,
                              void* d_out, int out_size, void* d_ws, size_t ws_size,
                              hipStream_t stream) {
    const float* x    = (const float*)d_in[0];
    const int*   eidx = (const int*)d_in[1];   // [2, E]
    // d_in[2] = edge_weight: unused by the reference
    const float* Wl1  = (const float*)d_in[3];
    const float* Wr1  = (const float*)d_in[4];
    const float* b1   = (const float*)d_in[5];
    const float* Wl2  = (const float*)d_in[6];
    const float* Wr2  = (const float*)d_in[7];
    const float* b2   = (const float*)d_in[8];
    const float* Wfc1 = (const float*)d_in[9];
    const float* bfc1 = (const float*)d_in[10];
    const float* Wfc2 = (const float*)d_in[11];
    const float* bfc2 = (const float*)d_in[12];

    const int N = in_sizes[0] / 64;
    const int E = in_sizes[2];
    const int* src = eidx;
    const int* dst = eidx + E;
    const int B = (N + S_NODES - 1) >> S_SHIFT;      // 782 buckets
    const int nscat = (E + CHUNK - 1) / CHUNK;       // 196 scatter blocks

    // workspace: [cursor 3136B pad->3200][deg N*4]  <-- one contiguous memset
    //            [c01 64B][ga N*4][q N*4][t1 N*4][inv N*4][gbc N*8][bucket B*CAP*4]
    char* ws = (char*)d_ws;
    size_t o = 0;
    auto take = [&](size_t bytes) { char* p = ws + o; o += (bytes + 127) & ~(size_t)127; return p; };
    int*      cursor = (int*)take(NBKT * 4);
    int*      deg    = (int*)take((size_t)N * 4);
    size_t zero_bytes = o;                            // memset covers cursor+deg
    float*    c01    = (float*)take(64);
    float*    ga     = (float*)take((size_t)N * 4);
    float*    q      = (float*)take((size_t)N * 4);
    float*    t1     = (float*)take((size_t)N * 4);
    float*    inv    = (float*)take((size_t)N * 4);
    float2*   gbc    = (float2*)take((size_t)N * 8);
    unsigned* bucket = (unsigned*)take((size_t)B * CAP * 4);

    hipMemsetAsync(ws, 0, zero_bytes, stream);

    fused_kernel<<<nscat + NDOTS, FTH, 0, stream>>>(
        x, src, dst, E, N, B, nscat, cursor, deg, bucket,
        Wl1, Wr1, b1, Wl2, Wr2, b2, Wfc1, bfc1, Wfc2, bfc2,
        ga, gbc, c01);

    aggA_kernel<<<B, ATH, 0, stream>>>(bucket, cursor, deg, gbc, ga, c01, q, t1, inv, N);
    aggB_kernel<<<B, ATH, 0, stream>>>(bucket, cursor, q, t1, inv, (float*)d_out, N);
}

// Round 5
// 172.488 us; speedup vs baseline: 3.5353x; 1.3179x over previous
//
#include <hip/hip_runtime.h>

#define S_SHIFT 8
#define S_NODES 256          // nodes per bucket (dst_local = dst & 255)
#define NBKT    400          // LDS array size (>= B = 391)
#define CAP     5120         // bucket capacity (mean ~4092, +25% slack)
#define CHUNK   8192         // edges per scatter block
#define NREP    8            // LDS accumulator replicas: one per wave (512 thr)
#define FTH     512          // fused kernel block size
#define NDOTS   160          // dots-role blocks

// ---------------- fused (EXACT round-0 winner: 51.9 us) ----------------
// Packed edge: (src << 8) | (dst & 255)   (src < 2^17 -> 25 bits)
__global__ __launch_bounds__(FTH) void fused_kernel(
    const float* __restrict__ x,
    const int* __restrict__ src, const int* __restrict__ dst,
    int E, int N, int B, int nscat,
    int* __restrict__ cursor, unsigned* __restrict__ bucket,
    const float* __restrict__ Wl1, const float* __restrict__ Wr1, const float* __restrict__ b1,
    const float* __restrict__ Wl2, const float* __restrict__ Wr2, const float* __restrict__ b2,
    const float* __restrict__ Wfc1, const float* __restrict__ bfc1,
    const float* __restrict__ Wfc2, const float* __restrict__ bfc2,
    float* __restrict__ ga, float2* __restrict__ gbc, float* __restrict__ c01)
{
    __shared__ int hist[NBKT], lbase[NBKT], lcur[NBKT];          // scatter role
    __shared__ __align__(16) float wv[192];                      // dots role
    __shared__ float uu[128], vl2[128], vr2[128], w2[32];
    int t = threadIdx.x;
    int l = t & 63;          // lane
    int w = t >> 6;          // wave (0..7)

    if ((int)blockIdx.x < nscat) {
        // ---------------- scatter role ----------------
        int e0 = blockIdx.x * CHUNK;
        int cnt = E - e0; if (cnt > CHUNK) cnt = CHUNK;
        for (int i = t; i < B; i += FTH) hist[i] = 0;
        __syncthreads();
        for (int i = t; i < cnt; i += FTH)
            atomicAdd(&hist[dst[e0 + i] >> S_SHIFT], 1);
        __syncthreads();
        for (int i = t; i < B; i += FTH) {
            lcur[i] = 0;
            if (hist[i] > 0) lbase[i] = atomicAdd(&cursor[i], hist[i]);
        }
        __syncthreads();
        for (int i = t; i < cnt; i += FTH) {
            int d = dst[e0 + i], s = src[e0 + i];   // L2-hot re-read
            int bb = d >> S_SHIFT;
            int off = atomicAdd(&lcur[bb], 1);
            bucket[(size_t)bb * CAP + (unsigned)(lbase[bb] + off)] =
                ((unsigned)s << S_SHIFT) | (unsigned)(d & (S_NODES - 1));
        }
    } else {
        // ---------------- fold role (redundant per block, coalesced wave-per-row) ----------------
        if (t < 32) w2[t] = Wfc2[t];
        __syncthreads();
        for (int j = 0; j < 16; ++j) {   // uu = Wfc1 @ Wfc2  (Wfc1 [128,32] row-major)
            int i = w + 8 * j;
            float p = (l < 32) ? Wfc1[i * 32 + l] * w2[l] : 0.f;
            for (int m = 16; m; m >>= 1) p += __shfl_xor(p, m);
            if (l == 0) uu[i] = p;
        }
        __syncthreads();
        for (int j = 0; j < 16; ++j) {   // vl2 = Wl2 @ uu, vr2 = Wr2 @ uu ([128,128] row-major)
            int i = w + 8 * j;
            float ua = uu[l], ub = uu[64 + l];
            float pa = Wl2[i * 128 + l] * ua + Wl2[i * 128 + 64 + l] * ub;
            float pb = Wr2[i * 128 + l] * ua + Wr2[i * 128 + 64 + l] * ub;
            for (int m = 32; m; m >>= 1) { pa += __shfl_xor(pa, m); pb += __shfl_xor(pb, m); }
            if (l == 0) { vl2[i] = pa; vr2[i] = pb; }
        }
        __syncthreads();
        for (int j = 0; j < 8; ++j) {    // wv = {w_a,w_b,w_c}  (Wl1/Wr1 [64,128] row-major)
            int i = w + 8 * j;
            float l1a = Wl1[i * 128 + l], l1b = Wl1[i * 128 + 64 + l];
            float r1a = Wr1[i * 128 + l], r1b = Wr1[i * 128 + 64 + l];
            float La = vl2[l], Lb = vl2[64 + l], Ra = vr2[l], Rb = vr2[64 + l];
            float pc = l1a * La + l1b * Lb;
            float pb = l1a * Ra + l1b * Rb + r1a * La + r1b * Lb;
            float pa = r1a * Ra + r1b * Rb;
            for (int m = 32; m; m >>= 1) {
                pa += __shfl_xor(pa, m); pb += __shfl_xor(pb, m); pc += __shfl_xor(pc, m);
            }
            if (l == 0) { wv[i] = pa; wv[64 + i] = pb; wv[128 + i] = pc; }
        }
        if ((int)blockIdx.x == nscat && w == 7) {   // c0, c1 (one block publishes)
            float p0 = b1[l] * vr2[l] + b1[64 + l] * vr2[64 + l]
                     + b2[l] * uu[l] + b2[64 + l] * uu[64 + l];
            if (l < 32) p0 += bfc1[l] * w2[l];
            float p1 = b1[l] * vl2[l] + b1[64 + l] * vl2[64 + l];
            for (int m = 32; m; m >>= 1) { p0 += __shfl_xor(p0, m); p1 += __shfl_xor(p1, m); }
            if (l == 0) { c01[0] = p0 + bfc2[0]; c01[1] = p1; }
        }
        __syncthreads();

        // ---------------- dots: 4 nodes/wave, float4, 16 lanes per node ----------------
        int fp = l & 15, sub = l >> 4;
        float4 wa4 = ((const float4*)wv)[fp];
        float4 wb4 = ((const float4*)wv)[16 + fp];
        float4 wc4 = ((const float4*)wv)[32 + fp];
        const float4* x4 = (const float4*)x;
        int Q = (N + 3) >> 2;
        for (int qd = ((int)blockIdx.x - nscat) * 8 + w; qd < Q; qd += NDOTS * 8) {
            int node = qd * 4 + sub;
            float a = 0.f, b = 0.f, c = 0.f;
            if (node < N) {
                float4 v = x4[(size_t)node * 16 + fp];
                a = v.x * wa4.x + v.y * wa4.y + v.z * wa4.z + v.w * wa4.w;
                b = v.x * wb4.x + v.y * wb4.y + v.z * wb4.z + v.w * wb4.w;
                c = v.x * wc4.x + v.y * wc4.y + v.z * wc4.z + v.w * wc4.w;
            }
            for (int m = 8; m; m >>= 1) {
                a += __shfl_xor(a, m); b += __shfl_xor(b, m); c += __shfl_xor(c, m);
            }
            if (fp == 0 && node < N) { ga[node] = a; gbc[node] = make_float2(b, c); }
        }
    }
}

// ---------------- aggA: TWO blocks per bucket (hi = blockIdx&1 selects edge half) ----------------
// Partials stored plain (no atomics, no pre-zero) to per-half arrays; finalize combines.
__global__ __launch_bounds__(512) void aggA_kernel(
    const unsigned* __restrict__ bucket, const int* __restrict__ cursor,
    const float2* __restrict__ gbc,
    float* __restrict__ sB0, float* __restrict__ sC0, int* __restrict__ cnt0,
    float* __restrict__ sB1, float* __restrict__ sC1, int* __restrict__ cnt1, int N)
{
    __shared__ float aB[NREP][S_NODES], aC[NREP][S_NODES];
    __shared__ int cnt[NREP][S_NODES];
    int t = threadIdx.x, blk = blockIdx.x;
    int b = blk >> 1, hi = blk & 1;
    int r = t >> 6;                       // private replica per wave
    float* aBf = (float*)aB; float* aCf = (float*)aC; int* cnf = (int*)cnt;
    for (int i = t; i < NREP * S_NODES; i += 512) { aBf[i] = 0.f; aCf[i] = 0.f; cnf[i] = 0; }
    __syncthreads();
    int n = cursor[b];
    int half = (((n + 1) >> 1) + 3) & ~3;            // 4-aligned split point
    if (half > n) half = n;
    int start = hi ? half : 0;
    int end   = hi ? n    : half;
    const unsigned* bp = bucket + (size_t)b * CAP;
    int m = end - start;
    int m4 = m & ~3;
    for (int i = start + 4 * t; i < start + m4; i += 4 * 512) {
        uint4 e4 = *(const uint4*)(bp + i);
        float2 g0 = gbc[e4.x >> S_SHIFT];
        float2 g1 = gbc[e4.y >> S_SHIFT];
        float2 g2 = gbc[e4.z >> S_SHIFT];
        float2 g3 = gbc[e4.w >> S_SHIFT];
        int d0 = e4.x & (S_NODES - 1), d1 = e4.y & (S_NODES - 1);
        int d2 = e4.z & (S_NODES - 1), d3 = e4.w & (S_NODES - 1);
        atomicAdd(&aB[r][d0], g0.x); atomicAdd(&aC[r][d0], g0.y); atomicAdd(&cnt[r][d0], 1);
        atomicAdd(&aB[r][d1], g1.x); atomicAdd(&aC[r][d1], g1.y); atomicAdd(&cnt[r][d1], 1);
        atomicAdd(&aB[r][d2], g2.x); atomicAdd(&aC[r][d2], g2.y); atomicAdd(&cnt[r][d2], 1);
        atomicAdd(&aB[r][d3], g3.x); atomicAdd(&aC[r][d3], g3.y); atomicAdd(&cnt[r][d3], 1);
    }
    int it = start + m4 + t;
    if (it < end) {
        unsigned uu = bp[it];
        float2 g = gbc[uu >> S_SHIFT];
        int dl = uu & (S_NODES - 1);
        atomicAdd(&aB[r][dl], g.x); atomicAdd(&aC[r][dl], g.y); atomicAdd(&cnt[r][dl], 1);
    }
    __syncthreads();
    if (t < S_NODES) {
        int node = (b << S_SHIFT) + t;
        if (node < N) {
            float sb = 0.f, sc = 0.f; int d = 0;
            #pragma unroll
            for (int k = 0; k < NREP; ++k) { sb += aB[k][t]; sc += aC[k][t]; d += cnt[k][t]; }
            if (hi == 0) { sB0[node] = sb; sC0[node] = sc; cnt0[node] = d; }
            else         { sB1[node] = sb; sC1[node] = sc; cnt1[node] = d; }
        }
    }
}

// ---------------- finalize: combine halves -> q, inv, out-init(t1). Fully coalesced. ----------------
__global__ __launch_bounds__(512) void finalize_kernel(
    const float* __restrict__ sB0, const float* __restrict__ sC0, const int* __restrict__ cnt0,
    const float* __restrict__ sB1, const float* __restrict__ sC1, const int* __restrict__ cnt1,
    const float* __restrict__ ga, const float* __restrict__ c01,
    float* __restrict__ q, float* __restrict__ inv, float* __restrict__ out, int N)
{
    int node = blockIdx.x * 512 + threadIdx.x;
    if (node < N) {
        int d = cnt0[node] + cnt1[node];
        float sb = sB0[node] + sB1[node];
        float sc = sC0[node] + sC1[node];
        float iv = 1.0f / ((d > 0) ? (float)d : 1.0f);
        q[node]   = iv * sc;
        inv[node] = iv;
        out[node] = ga[node] + iv * sb + c01[0] + (d > 0 ? c01[1] : 0.f);
    }
}

// ---------------- aggB: two blocks per bucket; combine via coalesced atomicAdd on out ----------------
__global__ __launch_bounds__(512) void aggB_kernel(
    const unsigned* __restrict__ bucket, const int* __restrict__ cursor,
    const float* __restrict__ q, const float* __restrict__ inv,
    float* __restrict__ out, int N)
{
    __shared__ float a2[NREP][S_NODES];
    int t = threadIdx.x, blk = blockIdx.x;
    int b = blk >> 1, hi = blk & 1;
    int r = t >> 6;
    float* a2f = (float*)a2;
    for (int i = t; i < NREP * S_NODES; i += 512) a2f[i] = 0.f;
    __syncthreads();
    int n = cursor[b];
    int half = (((n + 1) >> 1) + 3) & ~3;
    if (half > n) half = n;
    int start = hi ? half : 0;
    int end   = hi ? n    : half;
    const unsigned* bp = bucket + (size_t)b * CAP;
    int m = end - start;
    int m4 = m & ~3;
    for (int i = start + 4 * t; i < start + m4; i += 4 * 512) {
        uint4 e4 = *(const uint4*)(bp + i);
        float q0 = q[e4.x >> S_SHIFT], q1 = q[e4.y >> S_SHIFT];
        float q2 = q[e4.z >> S_SHIFT], q3 = q[e4.w >> S_SHIFT];
        atomicAdd(&a2[r][e4.x & (S_NODES - 1)], q0);
        atomicAdd(&a2[r][e4.y & (S_NODES - 1)], q1);
        atomicAdd(&a2[r][e4.z & (S_NODES - 1)], q2);
        atomicAdd(&a2[r][e4.w & (S_NODES - 1)], q3);
    }
    int it = start + m4 + t;
    if (it < end) {
        unsigned uu = bp[it];
        atomicAdd(&a2[r][uu & (S_NODES - 1)], q[uu >> S_SHIFT]);
    }
    __syncthreads();
    if (t < S_NODES) {
        int node = (b << S_SHIFT) + t;
        if (node < N) {
            float s2 = 0.f;
            #pragma unroll
            for (int k = 0; k < NREP; ++k) s2 += a2[k][t];
            atomicAdd(&out[node], inv[node] * s2);   // coalesced contiguous atomics (cheap)
        }
    }
}

extern "C" void kernel_launch(void* const* d_in, const int* in_sizes, int n_in,
                              void* d_out, int out_size, void* d_ws, size_t ws_size,
                              hipStream_t stream) {
    const float* x    = (const float*)d_in[0];
    const int*   eidx = (const int*)d_in[1];   // [2, E]
    // d_in[2] = edge_weight: unused by the reference
    const float* Wl1  = (const float*)d_in[3];
    const float* Wr1  = (const float*)d_in[4];
    const float* b1   = (const float*)d_in[5];
    const float* Wl2  = (const float*)d_in[6];
    const float* Wr2  = (const float*)d_in[7];
    const float* b2   = (const float*)d_in[8];
    const float* Wfc1 = (const float*)d_in[9];
    const float* bfc1 = (const float*)d_in[10];
    const float* Wfc2 = (const float*)d_in[11];
    const float* bfc2 = (const float*)d_in[12];

    const int N = in_sizes[0] / 64;
    const int E = in_sizes[2];
    const int* src = eidx;
    const int* dst = eidx + E;
    const int B = (N + S_NODES - 1) >> S_SHIFT;      // 391 buckets (<= NBKT)
    const int nscat = (E + CHUNK - 1) / CHUNK;       // 196 scatter blocks

    char* ws = (char*)d_ws;
    size_t o = 0;
    auto take = [&](size_t bytes) { char* p = ws + o; o += (bytes + 127) & ~(size_t)127; return p; };
    int*      cursor = (int*)take(NBKT * 4);          // only this needs zeroing
    float*    c01    = (float*)take(64);
    float*    ga     = (float*)take((size_t)N * 4);
    float*    q      = (float*)take((size_t)N * 4);
    float*    inv    = (float*)take((size_t)N * 4);
    float*    sB0    = (float*)take((size_t)N * 4);
    float*    sC0    = (float*)take((size_t)N * 4);
    int*      cnt0   = (int*)take((size_t)N * 4);
    float*    sB1    = (float*)take((size_t)N * 4);
    float*    sC1    = (float*)take((size_t)N * 4);
    int*      cnt1   = (int*)take((size_t)N * 4);
    float2*   gbc    = (float2*)take((size_t)N * 8);
    unsigned* bucket = (unsigned*)take((size_t)B * CAP * 4);

    hipMemsetAsync(cursor, 0, NBKT * 4, stream);

    fused_kernel<<<nscat + NDOTS, FTH, 0, stream>>>(
        x, src, dst, E, N, B, nscat, cursor, bucket,
        Wl1, Wr1, b1, Wl2, Wr2, b2, Wfc1, bfc1, Wfc2, bfc2,
        ga, gbc, c01);

    aggA_kernel<<<2 * B, 512, 0, stream>>>(bucket, cursor, gbc,
                                           sB0, sC0, cnt0, sB1, sC1, cnt1, N);

    finalize_kernel<<<(N + 511) / 512, 512, 0, stream>>>(
        sB0, sC0, cnt0, sB1, sC1, cnt1, ga, c01, q, inv, (float*)d_out, N);

    aggB_kernel<<<2 * B, 512, 0, stream>>>(bucket, cursor, q, inv, (float*)d_out, N);
}